// Round 7
// baseline (97.906 us; speedup 1.0000x reference)
//
#include <hip/hip_runtime.h>
#include <hip/hip_bf16.h>
#include <math.h>

#define B_ 2
#define T_ 512
#define D_ 64

typedef __attribute__((ext_vector_type(8))) short bf16x8;
typedef __attribute__((ext_vector_type(8))) unsigned short u16x8;
typedef __attribute__((ext_vector_type(4))) float f32x4;

static __device__ __forceinline__ unsigned short f2bf(float v) {
    __hip_bfloat16 h = __float2bfloat16(v);
    return *reinterpret_cast<unsigned short*>(&h);
}
static __device__ __forceinline__ float bf2f(unsigned short u) {
    return __uint_as_float(((unsigned)u) << 16);
}
static __device__ __forceinline__ unsigned short maxbits(unsigned short a, unsigned short b) {
    float m = fmaxf(bf2f(a), bf2f(b));
    return (unsigned short)(__float_as_uint(m) >> 16);
}
static __device__ __forceinline__ unsigned short minbits(unsigned short a, unsigned short b) {
    float m = fminf(bf2f(a), bf2f(b));
    return (unsigned short)(__float_as_uint(m) >> 16);
}

// ---------------------------------------------------------------------------
// Fused prep (267 heterogeneous blocks, 512 threads):
//  [0,8)    sparse tables tab[k][b][t][c], k=0..9, bf16
//  [8,11)   W fragment pack (full K)
//  [11,139) cur0bf[b][t][128] = bf16 suffix max/min of f (Hillis-Steele)
//  [139,171) intra[b][jt][jj][128] = running max/min within 32-j tile (scan)
//  [171,267) zero cur1 / cur2 / out
// ---------------------------------------------------------------------------
__global__ __launch_bounds__(512) void prep_kernel(
    const float* __restrict__ f,
    const float* __restrict__ W0, const float* __restrict__ W1, const float* __restrict__ W2,
    unsigned short* __restrict__ tmax, unsigned short* __restrict__ tmin,
    unsigned short* __restrict__ wf,
    unsigned short* __restrict__ cur0bf, unsigned short* __restrict__ intra,
    float* __restrict__ z0, float* __restrict__ z1, float* __restrict__ z2) {

    __shared__ unsigned short lmax[512][16];
    __shared__ unsigned short lmin[512][16];

    const int blk = blockIdx.x;
    const int tid = threadIdx.x;

    if (blk < 8) {
        const int b = blk & 1;
        const int c0 = (blk >> 1) * 16;
        const int t = tid;

        u16x8 mx[2], mn[2];
#pragma unroll
        for (int h = 0; h < 2; ++h) {
            const float* fp = &f[((size_t)(b * T_ + t) << 6) + c0 + h * 8];
#pragma unroll
            for (int e = 0; e < 8; ++e) {
                unsigned short u = f2bf(fp[e]);
                mx[h][e] = u; mn[h][e] = u;
            }
            size_t base = ((size_t)(b * T_ + t) << 6) + c0 + h * 8;
            *reinterpret_cast<u16x8*>(&tmax[base]) = mx[h];
            *reinterpret_cast<u16x8*>(&tmin[base]) = mn[h];
        }
        for (int k = 1; k <= 9; ++k) {
            *reinterpret_cast<u16x8*>(&lmax[t][0]) = mx[0];
            *reinterpret_cast<u16x8*>(&lmax[t][8]) = mx[1];
            *reinterpret_cast<u16x8*>(&lmin[t][0]) = mn[0];
            *reinterpret_cast<u16x8*>(&lmin[t][8]) = mn[1];
            __syncthreads();
            int t2 = t + (1 << (k - 1));
            if (t2 > T_ - 1) t2 = T_ - 1;
            u16x8 qx0 = *reinterpret_cast<const u16x8*>(&lmax[t2][0]);
            u16x8 qx1 = *reinterpret_cast<const u16x8*>(&lmax[t2][8]);
            u16x8 qn0 = *reinterpret_cast<const u16x8*>(&lmin[t2][0]);
            u16x8 qn1 = *reinterpret_cast<const u16x8*>(&lmin[t2][8]);
#pragma unroll
            for (int e = 0; e < 8; ++e) {
                mx[0][e] = maxbits(mx[0][e], qx0[e]);
                mx[1][e] = maxbits(mx[1][e], qx1[e]);
                mn[0][e] = minbits(mn[0][e], qn0[e]);
                mn[1][e] = minbits(mn[1][e], qn1[e]);
            }
            size_t base = ((size_t)((k * B_ + b) * T_ + t) << 6) + c0;
            *reinterpret_cast<u16x8*>(&tmax[base]) = mx[0];
            *reinterpret_cast<u16x8*>(&tmax[base + 8]) = mx[1];
            *reinterpret_cast<u16x8*>(&tmin[base]) = mn[0];
            *reinterpret_cast<u16x8*>(&tmin[base + 8]) = mn[1];
            __syncthreads();
        }
    } else if (blk < 11) {
        const int layer = blk - 8;
        const float* W = (layer == 0) ? W0 : ((layer == 1) ? W1 : W2);
        const int FRS = (layer == 0) ? 32 : 24;
        const int l = tid & 63;
        for (int fr = tid >> 6; fr < FRS; fr += 8) {
            int kt = fr >> 2, nt = fr & 3;
#pragma unroll
            for (int e = 0; e < 8; ++e) {
                int row = kt * 32 + ((l >> 4) << 3) + e;
                int col = nt * 16 + (l & 15);
                wf[((size_t)(layer * 32 + fr) * 64 + l) * 8 + e] = f2bf(W[row * 64 + col]);
            }
        }
    } else if (blk < 139) {
        const int x = blk - 11;
        const int c = x & 63, b = x >> 6;
        const int t = tid;
        float* smax = reinterpret_cast<float*>(lmax);
        float* smin = reinterpret_cast<float*>(lmin);
        float v = f[((size_t)(b * T_ + t) << 6) + c];
        smax[t] = v; smin[t] = v;
        __syncthreads();
        for (int off = 1; off < 512; off <<= 1) {
            float a = (t + off < 512) ? smax[t + off] : -1e30f;
            float m = (t + off < 512) ? smin[t + off] : 1e30f;
            __syncthreads();
            smax[t] = fmaxf(smax[t], a);
            smin[t] = fminf(smin[t], m);
            __syncthreads();
        }
        cur0bf[((size_t)(b * T_ + t) << 7) + c] = f2bf(smax[t]);
        cur0bf[((size_t)(b * T_ + t) << 7) + 64 + c] = f2bf(smin[t]);
    } else if (blk < 171) {
        const int x = blk - 139;
        const int jt = x & 15, b = x >> 4;
        const int jj = tid >> 4, c8 = tid & 15;
        const bool ismin = c8 >= 8;
        unsigned short (*sc)[128] = reinterpret_cast<unsigned short (*)[128]>(lmax);

        const float* fp = &f[((size_t)(b * T_ + jt * 32 + jj) << 6) + (c8 & 7) * 8];
        u16x8 r;
#pragma unroll
        for (int e = 0; e < 8; ++e) r[e] = f2bf(fp[e]);

#pragma unroll
        for (int off = 1; off < 32; off <<= 1) {
            *reinterpret_cast<u16x8*>(&sc[jj][c8 * 8]) = r;
            __syncthreads();
            if (jj >= off) {
                u16x8 q = *reinterpret_cast<const u16x8*>(&sc[jj - off][c8 * 8]);
#pragma unroll
                for (int e = 0; e < 8; ++e)
                    r[e] = ismin ? minbits(r[e], q[e]) : maxbits(r[e], q[e]);
            }
            __syncthreads();
        }
        *reinterpret_cast<u16x8*>(&intra[((size_t)((b * 16 + jt) * 32 + jj) << 7) + c8 * 8]) = r;
    } else {
        int fi = (blk - 171) * 512 + tid;
        float4 z = {0.f, 0.f, 0.f, 0.f};
        if (fi < 16384)       reinterpret_cast<float4*>(z0)[fi] = z;
        else if (fi < 32768)  reinterpret_cast<float4*>(z1)[fi - 16384] = z;
        else                  reinterpret_cast<float4*>(z2)[fi - 32768] = z;
    }
}

// ---------------------------------------------------------------------------
// Pair GEMM, jt-inner-loop persistent tiles.
// Grid = B * 128 it * 2 stripes.  Block = 4 waves; wave w owns row i = it*4+w.
// W fragments live in registers for the whole block.  Per-jt staging is
// double-buffered LDS with reg-staged async split; running max in registers;
// one atomicMax set per block at the end.
// ---------------------------------------------------------------------------
template <int C, bool FROM_TAB>
__global__ __launch_bounds__(256, 2) void pair_kernel(
    const unsigned short* __restrict__ tabmax,
    const unsigned short* __restrict__ tabmin,
    const unsigned short* __restrict__ cur0bf,  // [B,T,128] bf16
    const unsigned short* __restrict__ intra,   // [B,16,32,128] bf16
    const float* __restrict__ curprev,          // fp32 [B,T,64]; unused if FROM_TAB
    const unsigned short* __restrict__ wf,      // layer base, fragment order
    const float* __restrict__ bias,
    float* __restrict__ out) {

    constexpr int KTC = C / 32;       // 4 or 2
    constexpr int KT = KTC + 4;       // 8 or 6
    constexpr int CP = (C == 128) ? 136 : 72;

    const int bx = blockIdx.x;
    const int b = bx >> 8;
    const int rem = bx & 255;
    const int it = rem >> 1;
    const int h = rem & 1;
    const int i0 = it * 4;
    const int jt0 = it >> 3;
    const int start = jt0 + (h ? 1 : 2);     // first LDS-staged tile
    if (h && start > 15) return;             // empty stripe

    const int tid = threadIdx.x;
    const int l = tid & 63, w = tid >> 6;
    const int lg = l >> 4, li = l & 15;
    const int pi = i0 + w;
    const int jj_lo = tid >> 4, c8s = tid & 15;

    __shared__ unsigned short curl[2][32][CP];
    __shared__ unsigned short intr[2][32][136];
    __shared__ unsigned short pref[2][4][136];

    // ---- W fragments in registers, loaded once ----
    bf16x8 wfr[KT][4];
#pragma unroll
    for (int kt = 0; kt < KT; ++kt)
#pragma unroll
        for (int nt = 0; nt < 4; ++nt)
            wfr[kt][nt] = *reinterpret_cast<const bf16x8*>(&wf[(size_t)((kt * 4 + nt) * 64 + l) * 8]);

    float vmax[4] = {-1e9f, -1e9f, -1e9f, -1e9f};

    // staging registers
    u16x8 Rcur0, Rcur1;
    float4 Rf0, Rf1;
    u16x8 Rint0, Rint1;
    u16x8 Rpva, Rpvb;

    auto issue = [&](int jtn) {
        const int j0n = jtn * 32;
        if (FROM_TAB) {
            const unsigned short* cb = &cur0bf[((size_t)(b * T_ + j0n) << 7)];
            Rcur0 = *reinterpret_cast<const u16x8*>(&cb[(jj_lo << 7) + c8s * 8]);
            Rcur1 = *reinterpret_cast<const u16x8*>(&cb[((jj_lo + 16) << 7) + c8s * 8]);
        } else {
            const float* cp = &curprev[((size_t)(b * T_ + j0n + (tid >> 3)) << 6) + (tid & 7) * 8];
            Rf0 = *reinterpret_cast<const float4*>(cp);
            Rf1 = *reinterpret_cast<const float4*>(cp + 4);
        }
        const unsigned short* ib = &intra[((size_t)((b * 16 + jtn) * 32) << 7)];
        Rint0 = *reinterpret_cast<const u16x8*>(&ib[(jj_lo << 7) + c8s * 8]);
        Rint1 = *reinterpret_cast<const u16x8*>(&ib[((jj_lo + 16) << 7) + c8s * 8]);
        if (l < 16) {
            int len = j0n - pi;                 // >= 1 always (non-diag tiles)
            int kk = 31 - __clz(len);
            int t2 = j0n - (1 << kk);
            const unsigned short* tab = (li < 8) ? tabmax : tabmin;
            int cc = (li & 7) * 8;
            Rpva = *reinterpret_cast<const u16x8*>(&tab[(((size_t)(kk * B_ + b) * T_ + pi) << 6) + cc]);
            Rpvb = *reinterpret_cast<const u16x8*>(&tab[(((size_t)(kk * B_ + b) * T_ + t2) << 6) + cc]);
        }
    };

    auto wstage = [&](int p) {
        if (FROM_TAB) {
            *reinterpret_cast<u16x8*>(&curl[p][jj_lo][c8s * 8]) = Rcur0;
            *reinterpret_cast<u16x8*>(&curl[p][jj_lo + 16][c8s * 8]) = Rcur1;
        } else {
            u16x8 r;
            r[0] = f2bf(Rf0.x); r[1] = f2bf(Rf0.y); r[2] = f2bf(Rf0.z); r[3] = f2bf(Rf0.w);
            r[4] = f2bf(Rf1.x); r[5] = f2bf(Rf1.y); r[6] = f2bf(Rf1.z); r[7] = f2bf(Rf1.w);
            *reinterpret_cast<u16x8*>(&curl[p][tid >> 3][(tid & 7) * 8]) = r;
        }
        *reinterpret_cast<u16x8*>(&intr[p][jj_lo][c8s * 8]) = Rint0;
        *reinterpret_cast<u16x8*>(&intr[p][jj_lo + 16][c8s * 8]) = Rint1;
        if (l < 16) {
            u16x8 r;
#pragma unroll
            for (int e = 0; e < 8; ++e)
                r[e] = (li < 8) ? maxbits(Rpva[e], Rpvb[e]) : minbits(Rpva[e], Rpvb[e]);
            *reinterpret_cast<u16x8*>(&pref[p][w][li * 8]) = r;
        }
    };

    auto compute = [&](int p) {
        f32x4 acc[2][4];
#pragma unroll
        for (int s = 0; s < 2; ++s)
#pragma unroll
            for (int nt = 0; nt < 4; ++nt) acc[s][nt] = (f32x4){0.f, 0.f, 0.f, 0.f};

        u16x8 pv[4];
#pragma unroll
        for (int krt = 0; krt < 4; ++krt)
            pv[krt] = *reinterpret_cast<const u16x8*>(&pref[p][w][(krt * 4 + lg) * 8]);

#pragma unroll
        for (int kt = 0; kt < KT; ++kt) {
#pragma unroll
            for (int s = 0; s < 2; ++s) {
                const int pjj = 16 * s + li;
                bf16x8 av;
                if (kt < KTC) {
                    av = *reinterpret_cast<const bf16x8*>(&curl[p][pjj][kt * 32 + lg * 8]);
                } else {
                    const int krt = kt - KTC;
                    u16x8 iv = *reinterpret_cast<const u16x8*>(&intr[p][pjj][(krt * 4 + lg) * 8]);
                    if (krt < 2) {
#pragma unroll
                        for (int e = 0; e < 8; ++e) av[e] = (short)maxbits(iv[e], pv[krt][e]);
                    } else {
#pragma unroll
                        for (int e = 0; e < 8; ++e) av[e] = (short)minbits(iv[e], pv[krt][e]);
                    }
                }
#pragma unroll
                for (int nt = 0; nt < 4; ++nt)
                    acc[s][nt] = __builtin_amdgcn_mfma_f32_16x16x32_bf16(av, wfr[kt][nt], acc[s][nt], 0, 0, 0);
            }
        }
#pragma unroll
        for (int nt = 0; nt < 4; ++nt)
#pragma unroll
            for (int s = 0; s < 2; ++s)
#pragma unroll
                for (int r = 0; r < 4; ++r)
                    vmax[nt] = fmaxf(vmax[nt], acc[s][nt][r]);
    };

    // ================= main flow =================
    if (!h) {
        if (start <= 15) issue(start);
        // ---- diagonal tile jt0, straight from tables/global ----
        {
            const int j0 = jt0 * 32;
            f32x4 acc[2][4];
#pragma unroll
            for (int s = 0; s < 2; ++s)
#pragma unroll
                for (int nt = 0; nt < 4; ++nt) acc[s][nt] = (f32x4){0.f, 0.f, 0.f, 0.f};

#pragma unroll
            for (int kt = 0; kt < KT; ++kt) {
#pragma unroll
                for (int s = 0; s < 2; ++s) {
                    const int pjj = 16 * s + li;
                    bf16x8 av;
                    if (kt < KTC) {
                        if (FROM_TAB) {
                            av = *reinterpret_cast<const bf16x8*>(
                                &cur0bf[((size_t)(b * T_ + j0 + pjj) << 7) + kt * 32 + lg * 8]);
                        } else {
                            const float* cp = &curprev[((size_t)(b * T_ + j0 + pjj) << 6) + kt * 32 + lg * 8];
                            float4 v0 = *reinterpret_cast<const float4*>(cp);
                            float4 v1 = *reinterpret_cast<const float4*>(cp + 4);
                            av[0] = f2bf(v0.x); av[1] = f2bf(v0.y); av[2] = f2bf(v0.z); av[3] = f2bf(v0.w);
                            av[4] = f2bf(v1.x); av[5] = f2bf(v1.y); av[6] = f2bf(v1.z); av[7] = f2bf(v1.w);
                        }
                    } else {
                        const int krt = kt - KTC;
                        const int c8 = krt * 4 + lg;
                        const int pj = j0 + pjj;
                        const int je = (pj < pi) ? pi : pj;
                        const int len = je - pi + 1;
                        const int kk = 31 - __clz(len);
                        const int t2 = je + 1 - (1 << kk);
                        const unsigned short* tab = (krt < 2) ? tabmax : tabmin;
                        const int cc = (c8 & 7) * 8;
                        u16x8 va = *reinterpret_cast<const u16x8*>(&tab[(((size_t)(kk * B_ + b) * T_ + pi) << 6) + cc]);
                        u16x8 vb = *reinterpret_cast<const u16x8*>(&tab[(((size_t)(kk * B_ + b) * T_ + t2) << 6) + cc]);
                        if (krt < 2) {
#pragma unroll
                            for (int e = 0; e < 8; ++e) av[e] = (short)maxbits(va[e], vb[e]);
                        } else {
#pragma unroll
                            for (int e = 0; e < 8; ++e) av[e] = (short)minbits(va[e], vb[e]);
                        }
                    }
#pragma unroll
                    for (int nt = 0; nt < 4; ++nt)
                        acc[s][nt] = __builtin_amdgcn_mfma_f32_16x16x32_bf16(av, wfr[kt][nt], acc[s][nt], 0, 0, 0);
                }
            }
            // masked running max (only j >= i valid)
#pragma unroll
            for (int nt = 0; nt < 4; ++nt)
#pragma unroll
                for (int s = 0; s < 2; ++s)
#pragma unroll
                    for (int r = 0; r < 4; ++r) {
                        int jj = 16 * s + lg * 4 + r;
                        if (j0 + jj >= pi) vmax[nt] = fmaxf(vmax[nt], acc[s][nt][r]);
                    }
        }
    } else {
        issue(start);
    }

    int p = 0;
    for (int jt = start; jt <= 15; jt += 2) {
        wstage(p);
        __syncthreads();
        if (jt + 2 <= 15) issue(jt + 2);
        compute(p);
        p ^= 1;
    }

    // ---- epilogue: shfl-reduce across lane groups, bias+sigmoid, atomicMax ----
#pragma unroll
    for (int nt = 0; nt < 4; ++nt) {
        float vm = vmax[nt];
        vm = fmaxf(vm, __shfl_xor(vm, 16));
        vm = fmaxf(vm, __shfl_xor(vm, 32));
        if (l < 16) {
            int o = nt * 16 + li;
            float hh = 1.0f / (1.0f + __expf(-(vm + bias[o])));
            atomicMax((int*)out + (((size_t)(b * T_ + pi) << 6) + o), __float_as_int(hh));
        }
    }
}

// ---------------------------------------------------------------------------
extern "C" void kernel_launch(void* const* d_in, const int* in_sizes, int n_in,
                              void* d_out, int out_size, void* d_ws, size_t ws_size,
                              hipStream_t stream) {
    const float* f  = (const float*)d_in[0];
    const float* W0 = (const float*)d_in[1];
    const float* b0 = (const float*)d_in[2];
    const float* W1 = (const float*)d_in[3];
    const float* b1 = (const float*)d_in[4];
    const float* W2 = (const float*)d_in[5];
    const float* b2 = (const float*)d_in[6];
    float* outp = (float*)d_out;

    // workspace layout
    unsigned short* tabmax = (unsigned short*)d_ws;               // 10*B*T*64
    unsigned short* tabmin = tabmax + 10 * B_ * T_ * 64;          // 10*B*T*64
    unsigned short* wf     = tabmin + 10 * B_ * T_ * 64;          // 3*32*64*8
    unsigned short* cur0bf = wf + 3 * 32 * 64 * 8;                // B*T*128
    unsigned short* intra  = cur0bf + B_ * T_ * 128;              // B*16*32*128
    float* cur1 = (float*)(intra + B_ * 16 * 32 * 128);           // [B,T,64]
    float* cur2 = cur1 + B_ * T_ * 64;                            // [B,T,64]

    prep_kernel<<<dim3(267), dim3(512), 0, stream>>>(f, W0, W1, W2,
                                                     tabmax, tabmin, wf,
                                                     cur0bf, intra,
                                                     cur1, cur2, outp);

    const dim3 pgrid(B_ * 128 * 2);
    pair_kernel<128, true ><<<pgrid, dim3(256), 0, stream>>>(tabmax, tabmin, cur0bf, intra,
                                                             nullptr, wf + 0 * 32 * 64 * 8, b0, cur1);
    pair_kernel<64,  false><<<pgrid, dim3(256), 0, stream>>>(tabmax, tabmin, cur0bf, intra,
                                                             cur1, wf + 1 * 32 * 64 * 8, b1, cur2);
    pair_kernel<64,  false><<<pgrid, dim3(256), 0, stream>>>(tabmax, tabmin, cur0bf, intra,
                                                             cur2, wf + 2 * 32 * 64 * 8, b2, outp);
}